// Round 13
// baseline (99.658 us; speedup 1.0000x reference)
//
#include <hip/hip_runtime.h>
#include <hip/hip_bf16.h>

#define CIN 256
#define COUT 256
#define HH 32
#define WW 32
#define LL 4
#define NN 64   // B*L

typedef unsigned short u16;
typedef __attribute__((ext_vector_type(8))) short short8;    // 8 bf16 = one 16B unit
typedef __attribute__((ext_vector_type(4))) float f32x4;
typedef __attribute__((ext_vector_type(16))) float f32x16;   // 32x32 MFMA acc

typedef const __attribute__((address_space(1))) void gvoid_t;
typedef __attribute__((address_space(3))) void svoid_t;

static __device__ __forceinline__ u16 f2bf(float f) {
    __hip_bfloat16 h = __float2bfloat16(f);
    return *reinterpret_cast<u16*>(&h);
}
static __device__ __forceinline__ float bf2f(u16 b) {
    unsigned int u = ((unsigned int)b) << 16;
    return __uint_as_float(u);
}

// ---------------- Kernel 1 (fused prep): xb + pooled (blocks 0..2047),
//                  wb bf16 repack (2048..2303), twt transpose (2304..2559)
// xb branch: lane owns pos = k*256+tid -> consecutive lanes write consecutive 16B units.
__global__ __launch_bounds__(256) void prep_kernel(const float* __restrict__ x,
                                                   const float* __restrict__ weight,
                                                   const float* __restrict__ tconv_w,
                                                   float* __restrict__ pooled,
                                                   u16* __restrict__ xb,
                                                   u16* __restrict__ wb,
                                                   float* __restrict__ twt) {
    int bx = blockIdx.x;
    int tid = threadIdx.x;
    __shared__ float red[4][8];

    if (bx < 2048) {
        int n = bx >> 5, ko = bx & 31;
        int lane = tid & 63, wave = tid >> 6;
        const float* xn = x + ((size_t)n * CIN + ko * 8) * (HH * WW);

        float psum[8];
        #pragma unroll
        for (int ci = 0; ci < 8; ci++) psum[ci] = 0.f;

        size_t base = ((size_t)n * 32 + ko) * (34 * 34);   // units
        #pragma unroll
        for (int k = 0; k < 4; k++) {
            int pos = k * 256 + tid;
            int h = pos >> 5, w = pos & 31;
            short8 u;
            #pragma unroll
            for (int ci = 0; ci < 8; ci++) {
                float f = xn[ci * (HH * WW) + pos];
                psum[ci] += f;
                u[ci] = (short)f2bf(f);
            }
            *(short8*)(xb + (base + (size_t)(h + 1) * 34 + (w + 1)) * 8) = u;
        }
        if (tid < 132) {
            int cell = tid;
            int hp, wp;
            if (cell < 34)       { hp = 0;              wp = cell; }
            else if (cell < 68)  { hp = 33;             wp = cell - 34; }
            else if (cell < 100) { hp = cell - 68 + 1;  wp = 0; }
            else                 { hp = cell - 100 + 1; wp = 33; }
            short8 z = (short8){0, 0, 0, 0, 0, 0, 0, 0};
            *(short8*)(xb + (base + (size_t)hp * 34 + wp) * 8) = z;
        }
        #pragma unroll
        for (int ci = 0; ci < 8; ci++) {
            float s = psum[ci];
            #pragma unroll
            for (int off = 32; off > 0; off >>= 1) s += __shfl_down(s, off, 64);
            if (lane == 0) red[wave][ci] = s;
        }
        __syncthreads();
        if (tid < 8) {
            pooled[n * CIN + ko * 8 + tid] =
                (red[0][tid] + red[1][tid] + red[2][tid] + red[3][tid]) * (1.0f / (HH * WW));
        }
    } else if (bx < 2304) {
        int co = bx - 2048;
        int ci = tid;
        #pragma unroll
        for (int k = 0; k < 9; k++) {
            u16 v = f2bf(weight[((size_t)co * CIN + ci) * 9 + k]);
            size_t unit = ((size_t)k * 32 + (ci >> 3)) * COUT + co;
            wb[unit * 8 + (ci & 7)] = v;
        }
    } else {
        int co = bx - 2304;
        #pragma unroll
        for (int r = 0; r < 3; r++) {
            int idx = r * 256 + tid;           // 0..767
            int ci = idx / 3, k = idx - ci * 3;
            twt[((size_t)k * 256 + ci) * 256 + co] = tconv_w[(size_t)co * 768 + idx];
        }
    }
}

// ---------------- Kernel 2: temporal calib + gate (4-way parallel over co) ----------------
__global__ __launch_bounds__(256) void calib2_kernel(const float* __restrict__ pooled,
                                                     const float* __restrict__ twt,
                                                     const float* __restrict__ tconv_b,
                                                     const float* __restrict__ fc_w,
                                                     const float* __restrict__ fc_b,
                                                     float* __restrict__ scale,
                                                     float* __restrict__ gmul) {
    int n = blockIdx.x >> 2, coq = blockIdx.x & 3;
    int b = n / LL, t = n % LL;
    int i0 = max(t - 2, 0), i1 = max(t - 1, 0), i2 = t;
    __shared__ float p[3][CIN];
    __shared__ float red[4][64];
    int tid = threadIdx.x;
    p[0][tid] = pooled[(b * LL + i0) * CIN + tid];
    p[1][tid] = pooled[(b * LL + i1) * CIN + tid];
    p[2][tid] = pooled[(b * LL + i2) * CIN + tid];
    __syncthreads();
    int co = coq * 64 + (tid & 63);
    int c0 = (tid >> 6) * 64;
    float acc = 0.f;
    #pragma unroll 4
    for (int i = 0; i < 64; i++) {
        int ci = c0 + i;
        acc += p[0][ci] * twt[(size_t)(0 * 256 + ci) * 256 + co]
             + p[1][ci] * twt[(size_t)(1 * 256 + ci) * 256 + co]
             + p[2][ci] * twt[(size_t)(2 * 256 + ci) * 256 + co];
    }
    red[tid >> 6][tid & 63] = acc;
    __syncthreads();
    if (tid < 64) {
        float a = red[0][tid] + red[1][tid] + red[2][tid] + red[3][tid];
        scale[n * CIN + coq * 64 + tid] = a + tconv_b[coq * 64 + tid] + 1.0f;
    }
    if (coq == 0) {
        const float* fw = fc_w + tid * 3;
        float g = p[0][tid] * fw[0] + p[1][tid] * fw[1] + p[2][tid] * fw[2];
        #pragma unroll
        for (int off = 32; off > 0; off >>= 1) g += __shfl_down(g, off, 64);
        __shared__ float gw[4];
        if ((tid & 63) == 0) gw[tid >> 6] = g;
        __syncthreads();
        if (tid == 0) gmul[n] = gw[0] + gw[1] + gw[2] + gw[3] + fc_b[0] + 1.0f;
    }
}

// ---------------- Kernel 3: MFMA implicit-GEMM conv (R6/R10 structure, 32x32x16 MFMA) -------
// Block = (n, cog of 64 co, pg of 16 rows). 4 waves; wave = 64co x 128pos (4 rows x 32 cols).
// Scale applied to WEIGHTS at A-staging (transient reg path): A = bf16(bf16(w)*scale[n,ci]).
// A-LDS unit = (tap*4+k8)*66 + co ; B-LDS unit = k8*614 + lrow*34 + lcol (pad strides).
// 32x32x16 fragments: A row=lane&31 (co within 32-tile), k=(lane>>5)*8+e ;
//                     B col=lane&31 (pos col), k=(lane>>5)*8+e ;
//                     D col=lane&31, row=(reg&3)+8*(reg>>2)+4*(lane>>5).
#define AUNITS 2376
#define BUNITS 2560

__global__ __launch_bounds__(256, 2) void conv_mfma_kernel(
    const u16* __restrict__ xb, const u16* __restrict__ wb,
    const float* __restrict__ scale,
    const float* __restrict__ bias, const float* __restrict__ gmul,
    float* __restrict__ out) {
    // XCD-aware swizzle: 512 blocks, 8 XCDs -> all 8 blocks of one n on one XCD
    int blk = (blockIdx.x & 7) * 64 + (blockIdx.x >> 3);
    int n = blk >> 3, cog = (blk >> 1) & 3, pg = blk & 1;
    int r0 = pg * 16;
    int tid = threadIdx.x;
    int lane = tid & 63, wave = tid >> 6;
    int c32 = lane & 31, l2 = lane >> 5;   // 32x32 fragment coords
    int w4 = wave * 4;

    __shared__ short8 Alds[AUNITS];     // 38016 B
    __shared__ short8 Blds[BUNITS];     // 40960 B
    __shared__ float scale_lds[CIN];    // 1024 B

    scale_lds[tid] = scale[n * CIN + tid];

    f32x16 acc[2][4];                   // [co-tile of 32][output row] = 128 VGPR
    #pragma unroll
    for (int ct = 0; ct < 2; ct++)
        #pragma unroll
        for (int r = 0; r < 4; r++)
            #pragma unroll
            for (int e = 0; e < 16; e++) acc[ct][r][e] = 0.f;

    // kc-invariant staging offsets (identical to R10)
    int a_src = wave * 256 + cog * 64 + lane;   // + r*8192 + kc*1024
    int b_off[10];
    #pragma unroll
    for (int r = 0; r < 10; r++) {
        int u = r * 256 + tid;
        int ue = u < 2455 ? u : 2455;
        int k8 = ue / 614;
        int rem = ue - k8 * 614;
        if (rem > 611) rem = 611;
        b_off[r] = k8 * 1156 + rem;
    }
    int b_base0 = n * 36992 + r0 * 34;

    for (int kc = 0; kc < 8; kc++) {
        __syncthreads();
        // ---- stage B first (fire-and-forget into LDS)
        #pragma unroll
        for (int r = 0; r < 10; r++) {
            size_t gu = (size_t)(b_base0 + kc * 4624 + b_off[r]);
            __builtin_amdgcn_global_load_lds((gvoid_t*)(xb + gu * 8),
                (svoid_t*)&Blds[r * 256 + wave * 64], 16, 0, 0);
        }
        // ---- stage A via regs with weight-scaling; k8 == wave (thread-invariant)
        f32x4 s_lo = *(const f32x4*)&scale_lds[kc * 32 + wave * 8];
        f32x4 s_hi = *(const f32x4*)&scale_lds[kc * 32 + wave * 8 + 4];
        short8 wv[9];
        #pragma unroll
        for (int r = 0; r < 9; r++) {
            size_t gu = (size_t)(r * 8192 + kc * 1024 + a_src);
            wv[r] = *(const short8*)(wb + gu * 8);
        }
        #pragma unroll
        for (int r = 0; r < 9; r++) {
            short8 o;
            #pragma unroll
            for (int e = 0; e < 8; e++) {
                float s = (e < 4) ? s_lo[e] : s_hi[e - 4];
                o[e] = (short)f2bf(bf2f((u16)wv[r][e]) * s);
            }
            Alds[(r * 4 + wave) * 66 + lane] = o;   // lane==co; ds_write_b128
        }
        __syncthreads();

        #pragma unroll
        for (int dw = 0; dw < 3; dw++) {
            // B frags: 6 rows x 2 K16-steps; row-overlap reuse across dh
            short8 bfr[6][2];
            #pragma unroll
            for (int j = 0; j < 6; j++)
                #pragma unroll
                for (int s = 0; s < 2; s++) {
                    int k8 = s * 2 + l2;
                    int u = k8 * 614 + (w4 + j) * 34 + c32 + dw;
                    bfr[j][s] = Blds[u];
                }
            #pragma unroll
            for (int dh = 0; dh < 3; dh++) {
                int tap = dh * 3 + dw;
                #pragma unroll
                for (int s = 0; s < 2; s++)
                    #pragma unroll
                    for (int ct = 0; ct < 2; ct++) {
                        int ua = (tap * 4 + s * 2 + l2) * 66 + ct * 32 + c32;
                        short8 af = Alds[ua];
                        #pragma unroll
                        for (int r = 0; r < 4; r++)
                            acc[ct][r] = __builtin_amdgcn_mfma_f32_32x32x16_bf16(
                                af, bfr[r + dh][s], acc[ct][r], 0, 0, 0);
                    }
            }
        }
    }

    // ---- epilogue: D col=lane&31 -> pos, row=(reg&3)+8*(reg>>2)+4*l2 -> co
    float gm = gmul[n];
    #pragma unroll
    for (int ct = 0; ct < 2; ct++) {
        #pragma unroll
        for (int r = 0; r < 4; r++) {
            int orow = r0 + w4 + r;
            #pragma unroll
            for (int reg = 0; reg < 16; reg++) {
                int co = cog * 64 + ct * 32 + (reg & 3) + 8 * (reg >> 2) + 4 * l2;
                out[(((size_t)n * COUT + co) * HH + orow) * WW + c32] =
                    acc[ct][r][reg] + bias[co] * gm;
            }
        }
    }
}

// ---------------- Fallback path (ws too small): pool + calib + fp32 direct conv ----------------
__global__ __launch_bounds__(256) void pool_kernel(const float* __restrict__ x,
                                                   float* __restrict__ pooled) {
    int blk = blockIdx.x;
    const float* src = x + (size_t)blk * (HH * WW);
    int tid = threadIdx.x;
    float4 v = ((const float4*)src)[tid];
    float s = v.x + v.y + v.z + v.w;
    #pragma unroll
    for (int off = 32; off > 0; off >>= 1) s += __shfl_down(s, off, 64);
    __shared__ float ws[4];
    if ((tid & 63) == 0) ws[tid >> 6] = s;
    __syncthreads();
    if (tid == 0) pooled[blk] = (ws[0] + ws[1] + ws[2] + ws[3]) * (1.0f / (HH * WW));
}

__global__ __launch_bounds__(256) void calib_kernel(const float* __restrict__ pooled,
                                                    const float* __restrict__ tconv_w,
                                                    const float* __restrict__ tconv_b,
                                                    const float* __restrict__ fc_w,
                                                    const float* __restrict__ fc_b,
                                                    float* __restrict__ scale,
                                                    float* __restrict__ gmul) {
    int n = blockIdx.x;
    int b = n / LL, t = n % LL;
    int i0 = max(t - 2, 0), i1 = max(t - 1, 0), i2 = t;
    __shared__ float p[3][CIN];
    int tid = threadIdx.x;
    p[0][tid] = pooled[(b * LL + i0) * CIN + tid];
    p[1][tid] = pooled[(b * LL + i1) * CIN + tid];
    p[2][tid] = pooled[(b * LL + i2) * CIN + tid];
    __syncthreads();
    float acc = 0.f;
    for (int ci = 0; ci < CIN; ci++) {
        const float* w = tconv_w + ((size_t)tid * CIN + ci) * 3;
        acc += p[0][ci] * w[0] + p[1][ci] * w[1] + p[2][ci] * w[2];
    }
    scale[n * CIN + tid] = acc + tconv_b[tid] + 1.0f;
    const float* fw = fc_w + tid * 3;
    float g = p[0][tid] * fw[0] + p[1][tid] * fw[1] + p[2][tid] * fw[2];
    #pragma unroll
    for (int off = 32; off > 0; off >>= 1) g += __shfl_down(g, off, 64);
    __shared__ float gw[4];
    if ((tid & 63) == 0) gw[tid >> 6] = g;
    __syncthreads();
    if (tid == 0) gmul[n] = gw[0] + gw[1] + gw[2] + gw[3] + fc_b[0] + 1.0f;
}

__global__ __launch_bounds__(256) void conv_kernel(const float* __restrict__ x,
                                                   const float* __restrict__ weight,
                                                   const float* __restrict__ bias,
                                                   const float* __restrict__ scale,
                                                   const float* __restrict__ gmul,
                                                   float* __restrict__ out) {
    int blk = blockIdx.x;
    int n   = blk >> 5;
    int cog = (blk >> 3) & 3;
    int rg  = blk & 7;
    int co_base  = cog * 64;
    int row_base = rg * 4;
    int tid = threadIdx.x;
    int c   = tid & 31;
    int sub = tid >> 5;

    __shared__ float xin[6][34];
    __shared__ float wsh[9][65];

    float acc[8][4];
    #pragma unroll
    for (int j = 0; j < 8; j++)
        #pragma unroll
        for (int g = 0; g < 4; g++) acc[j][g] = 0.f;

    const float* xn = x + (size_t)n * CIN * HH * WW;

    for (int ci = 0; ci < CIN; ci++) {
        if (tid < 204) {
            float s = scale[n * CIN + ci];
            int lr = tid / 34, lc = tid % 34;
            int gr = row_base - 1 + lr, gc = lc - 1;
            float v = 0.f;
            if (gr >= 0 && gr < HH && gc >= 0 && gc < WW)
                v = xn[(size_t)ci * (HH * WW) + gr * WW + gc] * s;
            xin[lr][lc] = v;
        }
        for (int idx = tid; idx < 576; idx += 256) {
            int co = idx / 9, k = idx % 9;
            wsh[k][co] = weight[(size_t)(co_base + co) * (CIN * 9) + ci * 9 + k];
        }
        __syncthreads();
        float xr[6][3];
        #pragma unroll
        for (int r = 0; r < 6; r++)
            #pragma unroll
            for (int kw = 0; kw < 3; kw++) xr[r][kw] = xin[r][c + kw];
        #pragma unroll
        for (int j = 0; j < 8; j++) {
            float wv[9];
            #pragma unroll
            for (int k = 0; k < 9; k++) wv[k] = wsh[k][sub * 8 + j];
            #pragma unroll
            for (int g = 0; g < 4; g++)
                #pragma unroll
                for (int kh = 0; kh < 3; kh++)
                    #pragma unroll
                    for (int kw = 0; kw < 3; kw++)
                        acc[j][g] += xr[g + kh][kw] * wv[kh * 3 + kw];
        }
        __syncthreads();
    }
    float gm = gmul[n];
    #pragma unroll
    for (int j = 0; j < 8; j++) {
        int co = co_base + sub * 8 + j;
        float fb = bias[co] * gm;
        #pragma unroll
        for (int g = 0; g < 4; g++)
            out[(((size_t)n * COUT + co) * HH + (row_base + g)) * WW + c] = acc[j][g] + fb;
    }
}

extern "C" void kernel_launch(void* const* d_in, const int* in_sizes, int n_in,
                              void* d_out, int out_size, void* d_ws, size_t ws_size,
                              hipStream_t stream) {
    const float* x       = (const float*)d_in[0];
    const float* weight  = (const float*)d_in[1];
    const float* bias    = (const float*)d_in[2];
    const float* tconv_w = (const float*)d_in[3];
    const float* tconv_b = (const float*)d_in[4];
    const float* fc_w    = (const float*)d_in[5];
    const float* fc_b    = (const float*)d_in[6];
    float* out = (float*)d_out;

    char* wsb = (char*)d_ws;
    float* pooled = (float*)wsb;                       // 16384 f
    float* scale  = pooled + NN * CIN;                 // 16384 f
    float* gmul   = scale + NN * CIN;                  // 64 f
    const size_t XB_OFF = 131328;                      // bytes, 16-aligned
    const size_t XB_BYTES = (size_t)NN * 32 * 34 * 34 * 8 * 2;   // 37,879,808
    const size_t WB_OFF = XB_OFF + XB_BYTES;
    const size_t WB_BYTES = (size_t)9 * 32 * COUT * 8 * 2;       // 1,179,648
    const size_t TWT_OFF = WB_OFF + WB_BYTES;
    const size_t TWT_BYTES = (size_t)3 * 256 * 256 * 4;          // 786,432
    u16* xb = (u16*)(wsb + XB_OFF);
    u16* wb = (u16*)(wsb + WB_OFF);
    float* twt = (float*)(wsb + TWT_OFF);

    if (ws_size >= TWT_OFF + TWT_BYTES) {
        prep_kernel<<<2560, 256, 0, stream>>>(x, weight, tconv_w, pooled, xb, wb, twt);
        calib2_kernel<<<NN * 4, 256, 0, stream>>>(pooled, twt, tconv_b, fc_w, fc_b, scale, gmul);
        conv_mfma_kernel<<<NN * 4 * 2, 256, 0, stream>>>(xb, wb, scale, bias, gmul, out);
    } else {
        pool_kernel<<<NN * CIN, 256, 0, stream>>>(x, pooled);
        calib_kernel<<<NN, 256, 0, stream>>>(pooled, tconv_w, tconv_b, fc_w, fc_b, scale, gmul);
        conv_kernel<<<NN * 32, 256, 0, stream>>>(x, weight, bias, scale, gmul, out);
    }
}

// Round 14
// 92.997 us; speedup vs baseline: 1.0716x; 1.0716x over previous
//
#include <hip/hip_runtime.h>
#include <hip/hip_bf16.h>

#define CIN 256
#define COUT 256
#define HH 32
#define WW 32
#define LL 4
#define NN 64   // B*L

typedef unsigned short u16;
typedef __attribute__((ext_vector_type(8))) short short8;   // 8 bf16 = one 16B unit
typedef __attribute__((ext_vector_type(4))) float f32x4;

typedef const __attribute__((address_space(1))) void gvoid_t;
typedef __attribute__((address_space(3))) void svoid_t;

static __device__ __forceinline__ u16 f2bf(float f) {
    __hip_bfloat16 h = __float2bfloat16(f);
    return *reinterpret_cast<u16*>(&h);
}
static __device__ __forceinline__ float bf2f(u16 b) {
    unsigned int u = ((unsigned int)b) << 16;
    return __uint_as_float(u);
}

// ---------------- Kernel 1 (fused prep): xb + pooled (blocks 0..2047),
//                  wb bf16 repack (2048..2303), twt transpose (2304..2559)
// xb branch: lane owns pos = k*256+tid -> consecutive lanes write consecutive 16B units.
__global__ __launch_bounds__(256) void prep_kernel(const float* __restrict__ x,
                                                   const float* __restrict__ weight,
                                                   const float* __restrict__ tconv_w,
                                                   float* __restrict__ pooled,
                                                   u16* __restrict__ xb,
                                                   u16* __restrict__ wb,
                                                   float* __restrict__ twt) {
    int bx = blockIdx.x;
    int tid = threadIdx.x;
    __shared__ float red[4][8];

    if (bx < 2048) {
        int n = bx >> 5, ko = bx & 31;
        int lane = tid & 63, wave = tid >> 6;
        const float* xn = x + ((size_t)n * CIN + ko * 8) * (HH * WW);

        float psum[8];
        #pragma unroll
        for (int ci = 0; ci < 8; ci++) psum[ci] = 0.f;

        size_t base = ((size_t)n * 32 + ko) * (34 * 34);   // units
        #pragma unroll
        for (int k = 0; k < 4; k++) {
            int pos = k * 256 + tid;
            int h = pos >> 5, w = pos & 31;
            short8 u;
            #pragma unroll
            for (int ci = 0; ci < 8; ci++) {
                float f = xn[ci * (HH * WW) + pos];
                psum[ci] += f;
                u[ci] = (short)f2bf(f);
            }
            *(short8*)(xb + (base + (size_t)(h + 1) * 34 + (w + 1)) * 8) = u;
        }
        if (tid < 132) {
            int cell = tid;
            int hp, wp;
            if (cell < 34)       { hp = 0;              wp = cell; }
            else if (cell < 68)  { hp = 33;             wp = cell - 34; }
            else if (cell < 100) { hp = cell - 68 + 1;  wp = 0; }
            else                 { hp = cell - 100 + 1; wp = 33; }
            short8 z = (short8){0, 0, 0, 0, 0, 0, 0, 0};
            *(short8*)(xb + (base + (size_t)hp * 34 + wp) * 8) = z;
        }
        #pragma unroll
        for (int ci = 0; ci < 8; ci++) {
            float s = psum[ci];
            #pragma unroll
            for (int off = 32; off > 0; off >>= 1) s += __shfl_down(s, off, 64);
            if (lane == 0) red[wave][ci] = s;
        }
        __syncthreads();
        if (tid < 8) {
            pooled[n * CIN + ko * 8 + tid] =
                (red[0][tid] + red[1][tid] + red[2][tid] + red[3][tid]) * (1.0f / (HH * WW));
        }
    } else if (bx < 2304) {
        int co = bx - 2048;
        int ci = tid;
        #pragma unroll
        for (int k = 0; k < 9; k++) {
            u16 v = f2bf(weight[((size_t)co * CIN + ci) * 9 + k]);
            size_t unit = ((size_t)k * 32 + (ci >> 3)) * COUT + co;
            wb[unit * 8 + (ci & 7)] = v;
        }
    } else {
        int co = bx - 2304;
        #pragma unroll
        for (int r = 0; r < 3; r++) {
            int idx = r * 256 + tid;           // 0..767
            int ci = idx / 3, k = idx - ci * 3;
            twt[((size_t)k * 256 + ci) * 256 + co] = tconv_w[(size_t)co * 768 + idx];
        }
    }
}

// ---------------- Kernel 2: temporal calib + gate (4-way parallel over co) ----------------
__global__ __launch_bounds__(256) void calib2_kernel(const float* __restrict__ pooled,
                                                     const float* __restrict__ twt,
                                                     const float* __restrict__ tconv_b,
                                                     const float* __restrict__ fc_w,
                                                     const float* __restrict__ fc_b,
                                                     float* __restrict__ scale,
                                                     float* __restrict__ gmul) {
    int n = blockIdx.x >> 2, coq = blockIdx.x & 3;
    int b = n / LL, t = n % LL;
    int i0 = max(t - 2, 0), i1 = max(t - 1, 0), i2 = t;
    __shared__ float p[3][CIN];
    __shared__ float red[4][64];
    int tid = threadIdx.x;
    p[0][tid] = pooled[(b * LL + i0) * CIN + tid];
    p[1][tid] = pooled[(b * LL + i1) * CIN + tid];
    p[2][tid] = pooled[(b * LL + i2) * CIN + tid];
    __syncthreads();
    int co = coq * 64 + (tid & 63);
    int c0 = (tid >> 6) * 64;
    float acc = 0.f;
    #pragma unroll 4
    for (int i = 0; i < 64; i++) {
        int ci = c0 + i;
        acc += p[0][ci] * twt[(size_t)(0 * 256 + ci) * 256 + co]
             + p[1][ci] * twt[(size_t)(1 * 256 + ci) * 256 + co]
             + p[2][ci] * twt[(size_t)(2 * 256 + ci) * 256 + co];
    }
    red[tid >> 6][tid & 63] = acc;
    __syncthreads();
    if (tid < 64) {
        float a = red[0][tid] + red[1][tid] + red[2][tid] + red[3][tid];
        scale[n * CIN + coq * 64 + tid] = a + tconv_b[coq * 64 + tid] + 1.0f;
    }
    if (coq == 0) {
        const float* fw = fc_w + tid * 3;
        float g = p[0][tid] * fw[0] + p[1][tid] * fw[1] + p[2][tid] * fw[2];
        #pragma unroll
        for (int off = 32; off > 0; off >>= 1) g += __shfl_down(g, off, 64);
        __shared__ float gw[4];
        if ((tid & 63) == 0) gw[tid >> 6] = g;
        __syncthreads();
        if (tid == 0) gmul[n] = gw[0] + gw[1] + gw[2] + gw[3] + fc_b[0] + 1.0f;
    }
}

// ---------------- Kernel 3: MFMA implicit-GEMM conv (exact R6/R10 structure, 16x16x32) ------
// Block = (n, cog of 64 co, pg of 16 rows). 4 waves; wave = 64co x 128pos (4 rows x 32 cols).
// Scale applied to WEIGHTS at A-staging (transient reg path): A = bf16(bf16(w)*scale[n,ci]).
// A-LDS unit = (tap*4+k8)*66 + co ; B-LDS unit = k8*614 + lrow*34 + lcol (pad strides).
#define AUNITS 2376
#define BUNITS 2560

__global__ __launch_bounds__(256, 2) void conv_mfma_kernel(
    const u16* __restrict__ xb, const u16* __restrict__ wb,
    const float* __restrict__ scale,
    const float* __restrict__ bias, const float* __restrict__ gmul,
    float* __restrict__ out) {
    // XCD-aware swizzle: 512 blocks, 8 XCDs -> all 8 blocks of one n on one XCD
    int blk = (blockIdx.x & 7) * 64 + (blockIdx.x >> 3);
    int n = blk >> 3, cog = (blk >> 1) & 3, pg = blk & 1;
    int r0 = pg * 16;
    int tid = threadIdx.x;
    int lane = tid & 63, wave = tid >> 6;
    int l15 = lane & 15, l4 = lane >> 4;
    int w4 = wave * 4;

    __shared__ short8 Alds[AUNITS];     // 38016 B
    __shared__ short8 Blds[BUNITS];     // 40960 B
    __shared__ float scale_lds[CIN];    // 1024 B

    scale_lds[tid] = scale[n * CIN + tid];

    f32x4 acc[4][4][2];
    #pragma unroll
    for (int m = 0; m < 4; m++)
        #pragma unroll
        for (int r = 0; r < 4; r++)
            #pragma unroll
            for (int ch = 0; ch < 2; ch++) acc[m][r][ch] = (f32x4){0.f, 0.f, 0.f, 0.f};

    // kc-invariant staging offsets
    int a_src = wave * 256 + cog * 64 + lane;   // + r*8192 + kc*1024
    int b_off[10];
    #pragma unroll
    for (int r = 0; r < 10; r++) {
        int u = r * 256 + tid;
        int ue = u < 2455 ? u : 2455;
        int k8 = ue / 614;
        int rem = ue - k8 * 614;
        if (rem > 611) rem = 611;
        b_off[r] = k8 * 1156 + rem;
    }
    int b_base0 = n * 36992 + r0 * 34;

    for (int kc = 0; kc < 8; kc++) {
        __syncthreads();
        // ---- stage B first (fire-and-forget into LDS)
        #pragma unroll
        for (int r = 0; r < 10; r++) {
            size_t gu = (size_t)(b_base0 + kc * 4624 + b_off[r]);
            __builtin_amdgcn_global_load_lds((gvoid_t*)(xb + gu * 8),
                (svoid_t*)&Blds[r * 256 + wave * 64], 16, 0, 0);
        }
        // ---- stage A via regs with weight-scaling; k8 == wave (thread-invariant)
        f32x4 s_lo = *(const f32x4*)&scale_lds[kc * 32 + wave * 8];
        f32x4 s_hi = *(const f32x4*)&scale_lds[kc * 32 + wave * 8 + 4];
        short8 wv[9];
        #pragma unroll
        for (int r = 0; r < 9; r++) {
            size_t gu = (size_t)(r * 8192 + kc * 1024 + a_src);
            wv[r] = *(const short8*)(wb + gu * 8);
        }
        #pragma unroll
        for (int r = 0; r < 9; r++) {
            short8 o;
            #pragma unroll
            for (int e = 0; e < 8; e++) {
                float s = (e < 4) ? s_lo[e] : s_hi[e - 4];
                o[e] = (short)f2bf(bf2f((u16)wv[r][e]) * s);
            }
            Alds[(r * 4 + wave) * 66 + lane] = o;   // lane==co; ds_write_b128
        }
        __syncthreads();

        #pragma unroll
        for (int dw = 0; dw < 3; dw++) {
            short8 bfr[6][2];
            #pragma unroll
            for (int j = 0; j < 6; j++)
                #pragma unroll
                for (int ch = 0; ch < 2; ch++) {
                    int u = l4 * 614 + (w4 + j) * 34 + ch * 16 + l15 + dw;
                    bfr[j][ch] = Blds[u];
                }
            #pragma unroll
            for (int dh = 0; dh < 3; dh++) {
                int tap = dh * 3 + dw;
                #pragma unroll
                for (int m = 0; m < 4; m++) {
                    int ua = (tap * 4 + l4) * 66 + m * 16 + l15;
                    short8 af = Alds[ua];
                    #pragma unroll
                    for (int r = 0; r < 4; r++)
                        #pragma unroll
                        for (int ch = 0; ch < 2; ch++)
                            acc[m][r][ch] = __builtin_amdgcn_mfma_f32_16x16x32_bf16(
                                af, bfr[r + dh][ch], acc[m][r][ch], 0, 0, 0);
                }
            }
        }
    }

    // ---- epilogue: D row=(l>>4)*4+j -> co, col=l&15 -> pos
    float gm = gmul[n];
    #pragma unroll
    for (int m = 0; m < 4; m++) {
        #pragma unroll
        for (int r = 0; r < 4; r++) {
            int orow = r0 + w4 + r;
            #pragma unroll
            for (int ch = 0; ch < 2; ch++) {
                #pragma unroll
                for (int j = 0; j < 4; j++) {
                    int co = cog * 64 + m * 16 + l4 * 4 + j;
                    out[(((size_t)n * COUT + co) * HH + orow) * WW + ch * 16 + l15] =
                        acc[m][r][ch][j] + bias[co] * gm;
                }
            }
        }
    }
}

// ---------------- Fallback path (ws too small): pool + calib + fp32 direct conv ----------------
__global__ __launch_bounds__(256) void pool_kernel(const float* __restrict__ x,
                                                   float* __restrict__ pooled) {
    int blk = blockIdx.x;
    const float* src = x + (size_t)blk * (HH * WW);
    int tid = threadIdx.x;
    float4 v = ((const float4*)src)[tid];
    float s = v.x + v.y + v.z + v.w;
    #pragma unroll
    for (int off = 32; off > 0; off >>= 1) s += __shfl_down(s, off, 64);
    __shared__ float ws[4];
    if ((tid & 63) == 0) ws[tid >> 6] = s;
    __syncthreads();
    if (tid == 0) pooled[blk] = (ws[0] + ws[1] + ws[2] + ws[3]) * (1.0f / (HH * WW));
}

__global__ __launch_bounds__(256) void calib_kernel(const float* __restrict__ pooled,
                                                    const float* __restrict__ tconv_w,
                                                    const float* __restrict__ tconv_b,
                                                    const float* __restrict__ fc_w,
                                                    const float* __restrict__ fc_b,
                                                    float* __restrict__ scale,
                                                    float* __restrict__ gmul) {
    int n = blockIdx.x;
    int b = n / LL, t = n % LL;
    int i0 = max(t - 2, 0), i1 = max(t - 1, 0), i2 = t;
    __shared__ float p[3][CIN];
    int tid = threadIdx.x;
    p[0][tid] = pooled[(b * LL + i0) * CIN + tid];
    p[1][tid] = pooled[(b * LL + i1) * CIN + tid];
    p[2][tid] = pooled[(b * LL + i2) * CIN + tid];
    __syncthreads();
    float acc = 0.f;
    for (int ci = 0; ci < CIN; ci++) {
        const float* w = tconv_w + ((size_t)tid * CIN + ci) * 3;
        acc += p[0][ci] * w[0] + p[1][ci] * w[1] + p[2][ci] * w[2];
    }
    scale[n * CIN + tid] = acc + tconv_b[tid] + 1.0f;
    const float* fw = fc_w + tid * 3;
    float g = p[0][tid] * fw[0] + p[1][tid] * fw[1] + p[2][tid] * fw[2];
    #pragma unroll
    for (int off = 32; off > 0; off >>= 1) g += __shfl_down(g, off, 64);
    __shared__ float gw[4];
    if ((tid & 63) == 0) gw[tid >> 6] = g;
    __syncthreads();
    if (tid == 0) gmul[n] = gw[0] + gw[1] + gw[2] + gw[3] + fc_b[0] + 1.0f;
}

__global__ __launch_bounds__(256) void conv_kernel(const float* __restrict__ x,
                                                   const float* __restrict__ weight,
                                                   const float* __restrict__ bias,
                                                   const float* __restrict__ scale,
                                                   const float* __restrict__ gmul,
                                                   float* __restrict__ out) {
    int blk = blockIdx.x;
    int n   = blk >> 5;
    int cog = (blk >> 3) & 3;
    int rg  = blk & 7;
    int co_base  = cog * 64;
    int row_base = rg * 4;
    int tid = threadIdx.x;
    int c   = tid & 31;
    int sub = tid >> 5;

    __shared__ float xin[6][34];
    __shared__ float wsh[9][65];

    float acc[8][4];
    #pragma unroll
    for (int j = 0; j < 8; j++)
        #pragma unroll
        for (int g = 0; g < 4; g++) acc[j][g] = 0.f;

    const float* xn = x + (size_t)n * CIN * HH * WW;

    for (int ci = 0; ci < CIN; ci++) {
        if (tid < 204) {
            float s = scale[n * CIN + ci];
            int lr = tid / 34, lc = tid % 34;
            int gr = row_base - 1 + lr, gc = lc - 1;
            float v = 0.f;
            if (gr >= 0 && gr < HH && gc >= 0 && gc < WW)
                v = xn[(size_t)ci * (HH * WW) + gr * WW + gc] * s;
            xin[lr][lc] = v;
        }
        for (int idx = tid; idx < 576; idx += 256) {
            int co = idx / 9, k = idx % 9;
            wsh[k][co] = weight[(size_t)(co_base + co) * (CIN * 9) + ci * 9 + k];
        }
        __syncthreads();
        float xr[6][3];
        #pragma unroll
        for (int r = 0; r < 6; r++)
            #pragma unroll
            for (int kw = 0; kw < 3; kw++) xr[r][kw] = xin[r][c + kw];
        #pragma unroll
        for (int j = 0; j < 8; j++) {
            float wv[9];
            #pragma unroll
            for (int k = 0; k < 9; k++) wv[k] = wsh[k][sub * 8 + j];
            #pragma unroll
            for (int g = 0; g < 4; g++)
                #pragma unroll
                for (int kh = 0; kh < 3; kh++)
                    #pragma unroll
                    for (int kw = 0; kw < 3; kw++)
                        acc[j][g] += xr[g + kh][kw] * wv[kh * 3 + kw];
        }
        __syncthreads();
    }
    float gm = gmul[n];
    #pragma unroll
    for (int j = 0; j < 8; j++) {
        int co = co_base + sub * 8 + j;
        float fb = bias[co] * gm;
        #pragma unroll
        for (int g = 0; g < 4; g++)
            out[(((size_t)n * COUT + co) * HH + (row_base + g)) * WW + c] = acc[j][g] + fb;
    }
}

extern "C" void kernel_launch(void* const* d_in, const int* in_sizes, int n_in,
                              void* d_out, int out_size, void* d_ws, size_t ws_size,
                              hipStream_t stream) {
    const float* x       = (const float*)d_in[0];
    const float* weight  = (const float*)d_in[1];
    const float* bias    = (const float*)d_in[2];
    const float* tconv_w = (const float*)d_in[3];
    const float* tconv_b = (const float*)d_in[4];
    const float* fc_w    = (const float*)d_in[5];
    const float* fc_b    = (const float*)d_in[6];
    float* out = (float*)d_out;

    char* wsb = (char*)d_ws;
    float* pooled = (float*)wsb;                       // 16384 f
    float* scale  = pooled + NN * CIN;                 // 16384 f
    float* gmul   = scale + NN * CIN;                  // 64 f
    const size_t XB_OFF = 131328;                      // bytes, 16-aligned
    const size_t XB_BYTES = (size_t)NN * 32 * 34 * 34 * 8 * 2;   // 37,879,808
    const size_t WB_OFF = XB_OFF + XB_BYTES;
    const size_t WB_BYTES = (size_t)9 * 32 * COUT * 8 * 2;       // 1,179,648
    const size_t TWT_OFF = WB_OFF + WB_BYTES;
    const size_t TWT_BYTES = (size_t)3 * 256 * 256 * 4;          // 786,432
    u16* xb = (u16*)(wsb + XB_OFF);
    u16* wb = (u16*)(wsb + WB_OFF);
    float* twt = (float*)(wsb + TWT_OFF);

    if (ws_size >= TWT_OFF + TWT_BYTES) {
        prep_kernel<<<2560, 256, 0, stream>>>(x, weight, tconv_w, pooled, xb, wb, twt);
        calib2_kernel<<<NN * 4, 256, 0, stream>>>(pooled, twt, tconv_b, fc_w, fc_b, scale, gmul);
        conv_mfma_kernel<<<NN * 4 * 2, 256, 0, stream>>>(xb, wb, scale, bias, gmul, out);
    } else {
        pool_kernel<<<NN * CIN, 256, 0, stream>>>(x, pooled);
        calib_kernel<<<NN, 256, 0, stream>>>(pooled, tconv_w, tconv_b, fc_w, fc_b, scale, gmul);
        conv_kernel<<<NN * 32, 256, 0, stream>>>(x, weight, bias, scale, gmul, out);
    }
}